// Round 1
// baseline (4630.413 us; speedup 1.0000x reference)
//
#include <hip/hip_runtime.h>

#define N_NODES 20000
#define D 128
#define E_EDGES 320000
#define G 100
#define L_LAYERS 6
#define IN_DIM 5
#define ZROW (IN_DIM + D)
#define CUTOFF_V 10.0f
#define LOG2F_ 0.69314718055994530942f

__device__ __forceinline__ float sspf(float x) {
    // softplus(x) - log(2), numerically stable
    return fmaxf(x, 0.0f) + log1pf(__expf(-fabsf(x))) - LOG2F_;
}

#define FMA4(accj, av, w0, w1, w2, w3)                               \
    accj[0] += av.x * w0.x + av.y * w1.x + av.z * w2.x + av.w * w3.x; \
    accj[1] += av.x * w0.y + av.y * w1.y + av.z * w2.y + av.w * w3.y; \
    accj[2] += av.x * w0.z + av.y * w1.z + av.z * w2.z + av.w * w3.z; \
    accj[3] += av.x * w0.w + av.y * w1.w + av.z * w2.w + av.w * w3.w;

// ---------------------------------------------------------------------------
// h = z[:, :5] @ emblin_w.T + emblin_b + z[:, 5:]
// grid = N_NODES, block = 128
__global__ void embed_kernel(const float* __restrict__ z,
                             const float* __restrict__ ew,
                             const float* __restrict__ eb,
                             float* __restrict__ h) {
    int n = blockIdx.x;
    int d = threadIdx.x;
    const float* zr = z + (size_t)n * ZROW;
    float acc = eb[d] + zr[IN_DIM + d];
#pragma unroll
    for (int k = 0; k < IN_DIM; ++k) acc += zr[k] * ew[d * IN_DIM + k];
    h[(size_t)n * D + d] = acc;
}

// ---------------------------------------------------------------------------
// batched transpose: src[l][r][c] -> dst[l][c][r]
__global__ void transpose_kernel(const float* __restrict__ src,
                                 float* __restrict__ dst,
                                 int R, int C, int total) {
    int rc = R * C;
    for (int idx = blockIdx.x * blockDim.x + threadIdx.x; idx < total;
         idx += gridDim.x * blockDim.x) {
        int l = idx / rc;
        int rem = idx - l * rc;
        int r = rem / C;
        int c = rem - r * C;
        dst[(size_t)l * rc + c * R + r] = src[idx];
    }
}

// ---------------------------------------------------------------------------
// out = (SSP? ssp : id)(in @ W.T + bias), W given transposed as wT[k][d]
// 16 nodes per block, 256 threads: 32 d-threads (4 d each) x 8 n-threads (2 n each)
template <bool SSP, bool HASB>
__global__ __launch_bounds__(256) void node_gemm_kernel(
    const float* __restrict__ in, const float* __restrict__ wT,
    const float* __restrict__ bias, float* __restrict__ out) {
    __shared__ __align__(16) float tile[16][D];
    int t = threadIdx.x;
    int n0 = blockIdx.x * 16;
    const float4* in4 = (const float4*)(in + (size_t)n0 * D);
    float4* t4 = (float4*)(&tile[0][0]);
    t4[t] = in4[t];
    t4[t + 256] = in4[t + 256];
    __syncthreads();

    int dt = t & 31, nt = t >> 5;
    int d0 = dt * 4;
    float acc[2][4];
    if (HASB) {
        float4 bv = *(const float4*)(bias + d0);
#pragma unroll
        for (int n = 0; n < 2; ++n) {
            acc[n][0] = bv.x; acc[n][1] = bv.y; acc[n][2] = bv.z; acc[n][3] = bv.w;
        }
    } else {
#pragma unroll
        for (int n = 0; n < 2; ++n)
#pragma unroll
            for (int i = 0; i < 4; ++i) acc[n][i] = 0.0f;
    }
    for (int k = 0; k < D; k += 4) {
        float4 w0 = *(const float4*)(wT + (size_t)(k + 0) * D + d0);
        float4 w1 = *(const float4*)(wT + (size_t)(k + 1) * D + d0);
        float4 w2 = *(const float4*)(wT + (size_t)(k + 2) * D + d0);
        float4 w3 = *(const float4*)(wT + (size_t)(k + 3) * D + d0);
#pragma unroll
        for (int n = 0; n < 2; ++n) {
            float4 hv = *(const float4*)(&tile[nt * 2 + n][k]);
            FMA4(acc[n], hv, w0, w1, w2, w3);
        }
    }
#pragma unroll
    for (int n = 0; n < 2; ++n) {
        float4 o;
        if (SSP) {
            o.x = sspf(acc[n][0]); o.y = sspf(acc[n][1]);
            o.z = sspf(acc[n][2]); o.w = sspf(acc[n][3]);
        } else {
            o.x = acc[n][0]; o.y = acc[n][1]; o.z = acc[n][2]; o.w = acc[n][3];
        }
        *(float4*)(out + (size_t)(n0 + nt * 2 + n) * D + d0) = o;
    }
}

// ---------------------------------------------------------------------------
// h = h + concat([h, m]) @ lin_w.T + lin_b   (in place; wT is [256][128])
__global__ __launch_bounds__(256) void update_kernel(
    float* __restrict__ h, const float* __restrict__ m,
    const float* __restrict__ wT, const float* __restrict__ bias) {
    __shared__ __align__(16) float th[16][D];
    __shared__ __align__(16) float tm[16][D];
    int t = threadIdx.x;
    int n0 = blockIdx.x * 16;
    const float4* h4 = (const float4*)(h + (size_t)n0 * D);
    const float4* m4 = (const float4*)(m + (size_t)n0 * D);
    float4* th4 = (float4*)(&th[0][0]);
    float4* tm4 = (float4*)(&tm[0][0]);
    th4[t] = h4[t]; th4[t + 256] = h4[t + 256];
    tm4[t] = m4[t]; tm4[t + 256] = m4[t + 256];
    __syncthreads();

    int dt = t & 31, nt = t >> 5;
    int d0 = dt * 4;
    float acc[2][4];
    float4 bv = *(const float4*)(bias + d0);
#pragma unroll
    for (int n = 0; n < 2; ++n) {
        acc[n][0] = bv.x; acc[n][1] = bv.y; acc[n][2] = bv.z; acc[n][3] = bv.w;
    }
    for (int k = 0; k < D; k += 4) {
        float4 w0 = *(const float4*)(wT + (size_t)(k + 0) * D + d0);
        float4 w1 = *(const float4*)(wT + (size_t)(k + 1) * D + d0);
        float4 w2 = *(const float4*)(wT + (size_t)(k + 2) * D + d0);
        float4 w3 = *(const float4*)(wT + (size_t)(k + 3) * D + d0);
#pragma unroll
        for (int n = 0; n < 2; ++n) {
            float4 hv = *(const float4*)(&th[nt * 2 + n][k]);
            FMA4(acc[n], hv, w0, w1, w2, w3);
        }
    }
    for (int k = 0; k < D; k += 4) {
        float4 w0 = *(const float4*)(wT + (size_t)(D + k + 0) * D + d0);
        float4 w1 = *(const float4*)(wT + (size_t)(D + k + 1) * D + d0);
        float4 w2 = *(const float4*)(wT + (size_t)(D + k + 2) * D + d0);
        float4 w3 = *(const float4*)(wT + (size_t)(D + k + 3) * D + d0);
#pragma unroll
        for (int n = 0; n < 2; ++n) {
            float4 mv = *(const float4*)(&tm[nt * 2 + n][k]);
            FMA4(acc[n], mv, w0, w1, w2, w3);
        }
    }
#pragma unroll
    for (int n = 0; n < 2; ++n) {
        int nn = nt * 2 + n;
        float4 hv = *(const float4*)(&th[nn][d0]);
        float4 o;
        o.x = hv.x + acc[n][0]; o.y = hv.y + acc[n][1];
        o.z = hv.z + acc[n][2]; o.w = hv.w + acc[n][3];
        *(float4*)(h + (size_t)(n0 + nn) * D + d0) = o;
    }
}

// ---------------------------------------------------------------------------
// Fused edge kernel: per edge e,
//   u  = ssp(edge_attr[e] @ W1.T + b1)
//   Wf = (u @ W2.T + b2) * C[e]
//   atomicAdd(m_i[dst[e]], xf[src[e]] * Wf)
// 32 edges per block, 256 threads: 32 d-threads (4 d) x 8 e-threads (4 edges)
__global__ __launch_bounds__(256) void edge_kernel(
    const float* __restrict__ edge_attr, const int* __restrict__ ei,
    const float* __restrict__ el, const float* __restrict__ w1T,
    const float* __restrict__ b1, const float* __restrict__ w2T,
    const float* __restrict__ b2, const float* __restrict__ xf,
    float* __restrict__ m_i) {
    __shared__ __align__(16) float attr[32][G];
    __shared__ __align__(16) float uu[32][D];
    __shared__ int s_src[32];
    __shared__ int s_dst[32];
    __shared__ float s_C[32];

    int t = threadIdx.x;
    int e0 = blockIdx.x * 32;
    if (t < 32) {
        int e = e0 + t;
        s_src[t] = ei[e];
        s_dst[t] = ei[E_EDGES + e];
        s_C[t] = (el[e] <= CUTOFF_V) ? 1.0f : 0.0f;
    }
    for (int i = t; i < 32 * G; i += 256) {
        attr[i / G][i % G] = edge_attr[(size_t)e0 * G + i];
    }
    __syncthreads();

    int dt = t & 31, et = t >> 5;
    int d0 = dt * 4;
    int eb = et * 4;

    // phase 1: u = ssp(attr @ W1.T + b1)
    float acc[4][4];
    {
        float4 bv = *(const float4*)(b1 + d0);
#pragma unroll
        for (int j = 0; j < 4; ++j) {
            acc[j][0] = bv.x; acc[j][1] = bv.y; acc[j][2] = bv.z; acc[j][3] = bv.w;
        }
    }
    for (int g = 0; g < G; g += 4) {
        float4 w0 = *(const float4*)(w1T + (size_t)(g + 0) * D + d0);
        float4 w1 = *(const float4*)(w1T + (size_t)(g + 1) * D + d0);
        float4 w2 = *(const float4*)(w1T + (size_t)(g + 2) * D + d0);
        float4 w3 = *(const float4*)(w1T + (size_t)(g + 3) * D + d0);
#pragma unroll
        for (int j = 0; j < 4; ++j) {
            float4 av = *(const float4*)(&attr[eb + j][g]);
            FMA4(acc[j], av, w0, w1, w2, w3);
        }
    }
#pragma unroll
    for (int j = 0; j < 4; ++j) {
        float4 o;
        o.x = sspf(acc[j][0]); o.y = sspf(acc[j][1]);
        o.z = sspf(acc[j][2]); o.w = sspf(acc[j][3]);
        *(float4*)(&uu[eb + j][d0]) = o;
    }
    __syncthreads();

    // phase 2: Wf = u @ W2.T + b2
    {
        float4 bv = *(const float4*)(b2 + d0);
#pragma unroll
        for (int j = 0; j < 4; ++j) {
            acc[j][0] = bv.x; acc[j][1] = bv.y; acc[j][2] = bv.z; acc[j][3] = bv.w;
        }
    }
    for (int k = 0; k < D; k += 4) {
        float4 w0 = *(const float4*)(w2T + (size_t)(k + 0) * D + d0);
        float4 w1 = *(const float4*)(w2T + (size_t)(k + 1) * D + d0);
        float4 w2 = *(const float4*)(w2T + (size_t)(k + 2) * D + d0);
        float4 w3 = *(const float4*)(w2T + (size_t)(k + 3) * D + d0);
#pragma unroll
        for (int j = 0; j < 4; ++j) {
            float4 uv = *(const float4*)(&uu[eb + j][k]);
            FMA4(acc[j], uv, w0, w1, w2, w3);
        }
    }

    // scatter: m_i[dst] += xf[src] * Wf * C
#pragma unroll
    for (int j = 0; j < 4; ++j) {
        int e = eb + j;
        float c = s_C[e];
        int sr = s_src[e];
        int dn = s_dst[e];
        float4 xv = *(const float4*)(xf + (size_t)sr * D + d0);
        float* mp = m_i + (size_t)dn * D + d0;
        atomicAdd(mp + 0, acc[j][0] * c * xv.x);
        atomicAdd(mp + 1, acc[j][1] * c * xv.y);
        atomicAdd(mp + 2, acc[j][2] * c * xv.z);
        atomicAdd(mp + 3, acc[j][3] * c * xv.w);
    }
}

// ---------------------------------------------------------------------------
extern "C" void kernel_launch(void* const* d_in, const int* in_sizes, int n_in,
                              void* d_out, int out_size, void* d_ws, size_t ws_size,
                              hipStream_t stream) {
    const float* z        = (const float*)d_in[0];
    const int*   ei       = (const int*)d_in[1];
    const float* el       = (const float*)d_in[2];
    const float* ea       = (const float*)d_in[3];
    const float* emblin_w = (const float*)d_in[4];
    const float* emblin_b = (const float*)d_in[5];
    const float* mlp_w1   = (const float*)d_in[6];
    const float* mlp_b1   = (const float*)d_in[7];
    const float* mlp_w2   = (const float*)d_in[8];
    const float* mlp_b2   = (const float*)d_in[9];
    const float* lin1_w   = (const float*)d_in[10];
    const float* lin2_w   = (const float*)d_in[11];
    const float* lin2_b   = (const float*)d_in[12];
    const float* lin_w    = (const float*)d_in[13];
    const float* lin_b    = (const float*)d_in[14];
    (void)in_sizes; (void)n_in; (void)out_size; (void)ws_size;

    float* ws  = (float*)d_ws;
    float* h   = ws;                       // N*D
    float* m_i = h   + (size_t)N_NODES * D;
    float* xf  = m_i + (size_t)N_NODES * D;
    float* m   = xf  + (size_t)N_NODES * D;
    float* w1t = m   + (size_t)N_NODES * D;          // L*G*D
    float* w2t = w1t + (size_t)L_LAYERS * G * D;     // L*D*D
    float* l1t = w2t + (size_t)L_LAYERS * D * D;
    float* l2t = l1t + (size_t)L_LAYERS * D * D;
    float* lwt = l2t + (size_t)L_LAYERS * D * D;     // L*2D*D

    transpose_kernel<<<256, 256, 0, stream>>>(mlp_w1, w1t, D, G, L_LAYERS * D * G);
    transpose_kernel<<<256, 256, 0, stream>>>(mlp_w2, w2t, D, D, L_LAYERS * D * D);
    transpose_kernel<<<256, 256, 0, stream>>>(lin1_w, l1t, D, D, L_LAYERS * D * D);
    transpose_kernel<<<256, 256, 0, stream>>>(lin2_w, l2t, D, D, L_LAYERS * D * D);
    transpose_kernel<<<256, 256, 0, stream>>>(lin_w,  lwt, D, 2 * D, L_LAYERS * D * 2 * D);

    embed_kernel<<<N_NODES, D, 0, stream>>>(z, emblin_w, emblin_b, h);

    for (int l = 0; l < L_LAYERS; ++l) {
        hipMemsetAsync(m_i, 0, (size_t)N_NODES * D * sizeof(float), stream);
        node_gemm_kernel<false, false><<<N_NODES / 16, 256, 0, stream>>>(
            h, l1t + (size_t)l * D * D, nullptr, xf);
        edge_kernel<<<E_EDGES / 32, 256, 0, stream>>>(
            ea, ei, el, w1t + (size_t)l * G * D, mlp_b1 + (size_t)l * D,
            w2t + (size_t)l * D * D, mlp_b2 + (size_t)l * D, xf, m_i);
        node_gemm_kernel<true, true><<<N_NODES / 16, 256, 0, stream>>>(
            m_i, l2t + (size_t)l * D * D, lin2_b + (size_t)l * D, m);
        update_kernel<<<N_NODES / 16, 256, 0, stream>>>(
            h, m, lwt + (size_t)l * 2 * D * D, lin_b + (size_t)l * D);
    }

    hipMemcpyAsync(d_out, h, (size_t)N_NODES * D * sizeof(float),
                   hipMemcpyDeviceToDevice, stream);
}

// Round 2
// 2271.148 us; speedup vs baseline: 2.0388x; 2.0388x over previous
//
#include <hip/hip_runtime.h>

#define N_NODES 20000
#define D 128
#define E_EDGES 320000
#define G 100
#define L_LAYERS 6
#define IN_DIM 5
#define ZROW (IN_DIM + D)
#define CUTOFF_V 10.0f
#define LOG2F_ 0.69314718055994530942f

typedef __attribute__((ext_vector_type(8))) short bf16x8;
typedef __attribute__((ext_vector_type(4))) float f32x4;
typedef unsigned short ushort_t;
typedef unsigned int uint_t;

__device__ __forceinline__ float sspf(float x) {
    return fmaxf(x, 0.0f) + log1pf(__expf(-fabsf(x))) - LOG2F_;
}

__device__ __forceinline__ ushort_t f2bf(float f) {
    union { float f; uint_t u; } x; x.f = f;
    uint_t r = ((x.u >> 16) & 1u) + 0x7fffu;
    return (ushort_t)((x.u + r) >> 16);
}

#define FMA4(accj, av, w0, w1, w2, w3)                               \
    accj[0] += av.x * w0.x + av.y * w1.x + av.z * w2.x + av.w * w3.x; \
    accj[1] += av.x * w0.y + av.y * w1.y + av.z * w2.y + av.w * w3.y; \
    accj[2] += av.x * w0.z + av.y * w1.z + av.z * w2.z + av.w * w3.z; \
    accj[3] += av.x * w0.w + av.y * w1.w + av.z * w2.w + av.w * w3.w;

// ---------------------------------------------------------------------------
__global__ void embed_kernel(const float* __restrict__ z,
                             const float* __restrict__ ew,
                             const float* __restrict__ eb,
                             float* __restrict__ h) {
    int n = blockIdx.x;
    int d = threadIdx.x;
    const float* zr = z + (size_t)n * ZROW;
    float acc = eb[d] + zr[IN_DIM + d];
#pragma unroll
    for (int k = 0; k < IN_DIM; ++k) acc += zr[k] * ew[d * IN_DIM + k];
    h[(size_t)n * D + d] = acc;
}

// ---------------------------------------------------------------------------
__global__ void transpose_kernel(const float* __restrict__ src,
                                 float* __restrict__ dst,
                                 int R, int C, int total) {
    int rc = R * C;
    for (int idx = blockIdx.x * blockDim.x + threadIdx.x; idx < total;
         idx += gridDim.x * blockDim.x) {
        int l = idx / rc;
        int rem = idx - l * rc;
        int r = rem / C;
        int c = rem - r * C;
        dst[(size_t)l * rc + c * R + r] = src[idx];
    }
}

// mlp_w1 [L][D][G] -> bf16 [L][D][128] zero-padded in k
__global__ void convw1_kernel(const float* __restrict__ w1, ushort_t* __restrict__ out) {
    int idx = blockIdx.x * 256 + threadIdx.x;     // L*D*128 total
    int k = idx & 127;
    int nl = idx >> 7;
    out[idx] = (k < G) ? f2bf(w1[(size_t)nl * G + k]) : (ushort_t)0;
}

// mlp_w2 [L][D][D] -> bf16 same layout
__global__ void convw2_kernel(const float* __restrict__ w2, ushort_t* __restrict__ out) {
    int idx = blockIdx.x * 256 + threadIdx.x;     // L*D*D total
    out[idx] = f2bf(w2[idx]);
}

// ---------------------------------------------------------------------------
// CSR build (edge graph constant across layers)
__global__ void hist_kernel(const int* __restrict__ ei, int* __restrict__ deg) {
    int e = blockIdx.x * 256 + threadIdx.x;
    atomicAdd(&deg[ei[E_EDGES + e]], 1);
}

__global__ __launch_bounds__(1024) void scan_kernel(const int* __restrict__ deg,
                                                    int* __restrict__ row_start,
                                                    int* __restrict__ cursor) {
    __shared__ int wsum[16];
    int t = threadIdx.x;
    const int CH = (N_NODES + 1023) / 1024;   // 20
    int base = t * CH;
    int s = 0;
    for (int i = 0; i < CH; ++i) {
        int idx = base + i;
        if (idx < N_NODES) s += deg[idx];
    }
    int lane = t & 63, wid = t >> 6;
    int v = s;
    for (int o = 1; o < 64; o <<= 1) {
        int u = __shfl_up(v, o, 64);
        if (lane >= o) v += u;
    }
    if (lane == 63) wsum[wid] = v;
    __syncthreads();
    if (t == 0) {
        int acc = 0;
        for (int i = 0; i < 16; ++i) { int tmp = wsum[i]; wsum[i] = acc; acc += tmp; }
    }
    __syncthreads();
    int run = v - s + wsum[wid];   // exclusive prefix of this thread's chunk
    for (int i = 0; i < CH; ++i) {
        int idx = base + i;
        if (idx < N_NODES) {
            row_start[idx] = run;
            cursor[idx] = run;
            run += deg[idx];
        }
    }
    if (t == 0) row_start[N_NODES] = E_EDGES;
}

__global__ void scatter_perm_kernel(const int* __restrict__ ei, int* __restrict__ cursor,
                                    int* __restrict__ perm, int* __restrict__ src_p) {
    int e = blockIdx.x * 256 + threadIdx.x;
    int d = ei[E_EDGES + e];
    int p = atomicAdd(&cursor[d], 1);
    perm[p] = e;
    src_p[p] = ei[e];
}

// ---------------------------------------------------------------------------
// Fused edge MLP (bf16 MFMA): wf[i] = (ssp(attr[perm[i]] @ W1^T + b1) @ W2^T + b2) * C
// 64 edges/block, 256 threads = 4 waves, each wave a 16-row strip of 128 cols.
__global__ __launch_bounds__(256) void edge_mlp_kernel(
    const float* __restrict__ edge_attr, const float* __restrict__ el,
    const int* __restrict__ perm,
    const ushort_t* __restrict__ w1b, const float* __restrict__ b1,
    const ushort_t* __restrict__ w2b, const float* __restrict__ b2,
    ushort_t* __restrict__ wf) {
    __shared__ __align__(16) ushort_t sA[64 * 128];
    __shared__ __align__(16) ushort_t sU[64 * 128];
    __shared__ int s_pe[64];
    __shared__ float s_c[64];

    int t = threadIdx.x;
    int e0 = blockIdx.x * 64;
    if (t < 64) {
        int pe = perm[e0 + t];
        s_pe[t] = pe;
        s_c[t] = (el[pe] <= CUTOFF_V) ? 1.0f : 0.0f;
    }
    __syncthreads();

    // stage edge_attr rows -> bf16 LDS, zero-pad k in [100,128)
    {
        int r = t >> 2, qb = (t & 3) * 8;     // 4 threads/row, 8 float4 each
        const float4* srcp = (const float4*)(edge_attr + (size_t)s_pe[r] * G);
        ushort_t* dstp = sA + r * 128 + qb * 4;
#pragma unroll
        for (int i = 0; i < 8; ++i) {
            int q = qb + i;
            float4 v = (q < 25) ? srcp[q] : make_float4(0.f, 0.f, 0.f, 0.f);
            dstp[i * 4 + 0] = f2bf(v.x);
            dstp[i * 4 + 1] = f2bf(v.y);
            dstp[i * 4 + 2] = f2bf(v.z);
            dstp[i * 4 + 3] = f2bf(v.w);
        }
    }
    __syncthreads();

    int lane = t & 63, wid = t >> 6;
    int c = lane & 15, quad = lane >> 4;
    int arow = wid * 16 + c;     // A fragment row (m = lane&15)

    f32x4 acc[8];
#pragma unroll
    for (int i = 0; i < 8; ++i) acc[i] = (f32x4){0.f, 0.f, 0.f, 0.f};

    // GEMM1: sA @ W1^T
    for (int ks = 0; ks < 4; ++ks) {
        int koff = ks * 32 + quad * 8;
        bf16x8 a = *(const bf16x8*)(sA + arow * 128 + koff);
#pragma unroll
        for (int ct = 0; ct < 8; ++ct) {
            bf16x8 b = *(const bf16x8*)(w1b + (size_t)(ct * 16 + c) * 128 + koff);
            acc[ct] = __builtin_amdgcn_mfma_f32_16x16x32_bf16(a, b, acc[ct], 0, 0, 0);
        }
    }
    // epilogue 1: ssp(acc + b1) -> sU (bf16)
#pragma unroll
    for (int ct = 0; ct < 8; ++ct) {
        float bv = b1[ct * 16 + c];
#pragma unroll
        for (int r = 0; r < 4; ++r) {
            int rr = wid * 16 + quad * 4 + r;
            sU[rr * 128 + ct * 16 + c] = f2bf(sspf(acc[ct][r] + bv));
        }
    }
    __syncthreads();

    // GEMM2: sU @ W2^T
#pragma unroll
    for (int i = 0; i < 8; ++i) acc[i] = (f32x4){0.f, 0.f, 0.f, 0.f};
    for (int ks = 0; ks < 4; ++ks) {
        int koff = ks * 32 + quad * 8;
        bf16x8 a = *(const bf16x8*)(sU + arow * 128 + koff);
#pragma unroll
        for (int ct = 0; ct < 8; ++ct) {
            bf16x8 b = *(const bf16x8*)(w2b + (size_t)(ct * 16 + c) * 128 + koff);
            acc[ct] = __builtin_amdgcn_mfma_f32_16x16x32_bf16(a, b, acc[ct], 0, 0, 0);
        }
    }
    __syncthreads();   // everyone done reading sU before reuse

    // epilogue 2: (acc + b2) * C -> sU (bf16)
#pragma unroll
    for (int ct = 0; ct < 8; ++ct) {
        float bv = b2[ct * 16 + c];
#pragma unroll
        for (int r = 0; r < 4; ++r) {
            int rr = wid * 16 + quad * 4 + r;
            sU[rr * 128 + ct * 16 + c] = f2bf((acc[ct][r] + bv) * s_c[rr]);
        }
    }
    __syncthreads();

    // coalesced copy sU -> wf (16 KB/block)
    {
        const uint4* s4 = (const uint4*)sU;
        uint4* g4 = (uint4*)(wf + (size_t)e0 * 128);
#pragma unroll
        for (int i = 0; i < 4; ++i) g4[t + i * 256] = s4[t + i * 256];
    }
}

// ---------------------------------------------------------------------------
// Segment sum without atomics: one wave per dst node, 2 cols/lane.
__global__ __launch_bounds__(256) void segsum_kernel(
    const ushort_t* __restrict__ wf, const float* __restrict__ xf,
    const int* __restrict__ row_start, const int* __restrict__ src_p,
    float* __restrict__ m_i) {
    int t = threadIdx.x;
    int lane = t & 63;
    int n = blockIdx.x * 4 + (t >> 6);
    int beg = row_start[n], end = row_start[n + 1];
    float2 acc = make_float2(0.f, 0.f);
    for (int i = beg; i < end; ++i) {
        uint_t w = *(const uint_t*)(wf + (size_t)i * 128 + lane * 2);
        float2 x = *(const float2*)(xf + (size_t)src_p[i] * 128 + lane * 2);
        float w0 = __uint_as_float(w << 16);
        float w1 = __uint_as_float(w & 0xffff0000u);
        acc.x += w0 * x.x;
        acc.y += w1 * x.y;
    }
    *(float2*)(m_i + (size_t)n * 128 + lane * 2) = acc;
}

// ---------------------------------------------------------------------------
template <bool SSP, bool HASB>
__global__ __launch_bounds__(256) void node_gemm_kernel(
    const float* __restrict__ in, const float* __restrict__ wT,
    const float* __restrict__ bias, float* __restrict__ out) {
    __shared__ __align__(16) float tile[16][D];
    int t = threadIdx.x;
    int n0 = blockIdx.x * 16;
    const float4* in4 = (const float4*)(in + (size_t)n0 * D);
    float4* t4 = (float4*)(&tile[0][0]);
    t4[t] = in4[t];
    t4[t + 256] = in4[t + 256];
    __syncthreads();

    int dt = t & 31, nt = t >> 5;
    int d0 = dt * 4;
    float acc[2][4];
    if (HASB) {
        float4 bv = *(const float4*)(bias + d0);
#pragma unroll
        for (int n = 0; n < 2; ++n) {
            acc[n][0] = bv.x; acc[n][1] = bv.y; acc[n][2] = bv.z; acc[n][3] = bv.w;
        }
    } else {
#pragma unroll
        for (int n = 0; n < 2; ++n)
#pragma unroll
            for (int i = 0; i < 4; ++i) acc[n][i] = 0.0f;
    }
    for (int k = 0; k < D; k += 4) {
        float4 w0 = *(const float4*)(wT + (size_t)(k + 0) * D + d0);
        float4 w1 = *(const float4*)(wT + (size_t)(k + 1) * D + d0);
        float4 w2 = *(const float4*)(wT + (size_t)(k + 2) * D + d0);
        float4 w3 = *(const float4*)(wT + (size_t)(k + 3) * D + d0);
#pragma unroll
        for (int n = 0; n < 2; ++n) {
            float4 hv = *(const float4*)(&tile[nt * 2 + n][k]);
            FMA4(acc[n], hv, w0, w1, w2, w3);
        }
    }
#pragma unroll
    for (int n = 0; n < 2; ++n) {
        float4 o;
        if (SSP) {
            o.x = sspf(acc[n][0]); o.y = sspf(acc[n][1]);
            o.z = sspf(acc[n][2]); o.w = sspf(acc[n][3]);
        } else {
            o.x = acc[n][0]; o.y = acc[n][1]; o.z = acc[n][2]; o.w = acc[n][3];
        }
        *(float4*)(out + (size_t)(n0 + nt * 2 + n) * D + d0) = o;
    }
}

// ---------------------------------------------------------------------------
__global__ __launch_bounds__(256) void update_kernel(
    float* __restrict__ h, const float* __restrict__ m,
    const float* __restrict__ wT, const float* __restrict__ bias) {
    __shared__ __align__(16) float th[16][D];
    __shared__ __align__(16) float tm[16][D];
    int t = threadIdx.x;
    int n0 = blockIdx.x * 16;
    const float4* h4 = (const float4*)(h + (size_t)n0 * D);
    const float4* m4 = (const float4*)(m + (size_t)n0 * D);
    float4* th4 = (float4*)(&th[0][0]);
    float4* tm4 = (float4*)(&tm[0][0]);
    th4[t] = h4[t]; th4[t + 256] = h4[t + 256];
    tm4[t] = m4[t]; tm4[t + 256] = m4[t + 256];
    __syncthreads();

    int dt = t & 31, nt = t >> 5;
    int d0 = dt * 4;
    float acc[2][4];
    float4 bv = *(const float4*)(bias + d0);
#pragma unroll
    for (int n = 0; n < 2; ++n) {
        acc[n][0] = bv.x; acc[n][1] = bv.y; acc[n][2] = bv.z; acc[n][3] = bv.w;
    }
    for (int k = 0; k < D; k += 4) {
        float4 w0 = *(const float4*)(wT + (size_t)(k + 0) * D + d0);
        float4 w1 = *(const float4*)(wT + (size_t)(k + 1) * D + d0);
        float4 w2 = *(const float4*)(wT + (size_t)(k + 2) * D + d0);
        float4 w3 = *(const float4*)(wT + (size_t)(k + 3) * D + d0);
#pragma unroll
        for (int n = 0; n < 2; ++n) {
            float4 hv = *(const float4*)(&th[nt * 2 + n][k]);
            FMA4(acc[n], hv, w0, w1, w2, w3);
        }
    }
    for (int k = 0; k < D; k += 4) {
        float4 w0 = *(const float4*)(wT + (size_t)(D + k + 0) * D + d0);
        float4 w1 = *(const float4*)(wT + (size_t)(D + k + 1) * D + d0);
        float4 w2 = *(const float4*)(wT + (size_t)(D + k + 2) * D + d0);
        float4 w3 = *(const float4*)(wT + (size_t)(D + k + 3) * D + d0);
#pragma unroll
        for (int n = 0; n < 2; ++n) {
            float4 mv = *(const float4*)(&tm[nt * 2 + n][k]);
            FMA4(acc[n], mv, w0, w1, w2, w3);
        }
    }
#pragma unroll
    for (int n = 0; n < 2; ++n) {
        int nn = nt * 2 + n;
        float4 hv = *(const float4*)(&th[nn][d0]);
        float4 o;
        o.x = hv.x + acc[n][0]; o.y = hv.y + acc[n][1];
        o.z = hv.z + acc[n][2]; o.w = hv.w + acc[n][3];
        *(float4*)(h + (size_t)(n0 + nn) * D + d0) = o;
    }
}

// ---------------------------------------------------------------------------
extern "C" void kernel_launch(void* const* d_in, const int* in_sizes, int n_in,
                              void* d_out, int out_size, void* d_ws, size_t ws_size,
                              hipStream_t stream) {
    const float* z        = (const float*)d_in[0];
    const int*   ei       = (const int*)d_in[1];
    const float* el       = (const float*)d_in[2];
    const float* ea       = (const float*)d_in[3];
    const float* emblin_w = (const float*)d_in[4];
    const float* emblin_b = (const float*)d_in[5];
    const float* mlp_w1   = (const float*)d_in[6];
    const float* mlp_b1   = (const float*)d_in[7];
    const float* mlp_w2   = (const float*)d_in[8];
    const float* mlp_b2   = (const float*)d_in[9];
    const float* lin1_w   = (const float*)d_in[10];
    const float* lin2_w   = (const float*)d_in[11];
    const float* lin2_b   = (const float*)d_in[12];
    const float* lin_w    = (const float*)d_in[13];
    const float* lin_b    = (const float*)d_in[14];
    (void)in_sizes; (void)n_in; (void)out_size; (void)ws_size;

    const size_t ND = (size_t)N_NODES * D;
    float* ws  = (float*)d_ws;
    float* h   = ws;                 // N*D
    float* xf  = h   + ND;
    float* m_i = xf  + ND;
    float* m   = m_i + ND;
    float* l1t = m   + ND;                              // L*D*D fp32
    float* l2t = l1t + (size_t)L_LAYERS * D * D;
    float* lwt = l2t + (size_t)L_LAYERS * D * D;        // L*2D*D
    float* fend = lwt + (size_t)L_LAYERS * 2 * D * D;

    ushort_t* w1b  = (ushort_t*)fend;                   // L*D*128 bf16
    ushort_t* w2b  = w1b + (size_t)L_LAYERS * D * 128;  // L*D*D bf16
    ushort_t* wf   = w2b + (size_t)L_LAYERS * D * D;    // E*D bf16
    int* ibase     = (int*)(wf + (size_t)E_EDGES * D);
    int* deg       = ibase;                  // N
    int* row_start = deg + N_NODES;          // N+1
    int* cursor    = row_start + N_NODES + 1;
    int* perm      = cursor + N_NODES;       // E
    int* src_p     = perm + E_EDGES;         // E

    // one-time weight prep
    transpose_kernel<<<256, 256, 0, stream>>>(lin1_w, l1t, D, D, L_LAYERS * D * D);
    transpose_kernel<<<256, 256, 0, stream>>>(lin2_w, l2t, D, D, L_LAYERS * D * D);
    transpose_kernel<<<256, 256, 0, stream>>>(lin_w,  lwt, D, 2 * D, L_LAYERS * D * 2 * D);
    convw1_kernel<<<(L_LAYERS * D * 128) / 256, 256, 0, stream>>>(mlp_w1, w1b);
    convw2_kernel<<<(L_LAYERS * D * D) / 256, 256, 0, stream>>>(mlp_w2, w2b);

    // CSR build
    hipMemsetAsync(deg, 0, (size_t)N_NODES * sizeof(int), stream);
    hist_kernel<<<E_EDGES / 256, 256, 0, stream>>>(ei, deg);
    scan_kernel<<<1, 1024, 0, stream>>>(deg, row_start, cursor);
    scatter_perm_kernel<<<E_EDGES / 256, 256, 0, stream>>>(ei, cursor, perm, src_p);

    embed_kernel<<<N_NODES, D, 0, stream>>>(z, emblin_w, emblin_b, h);

    for (int l = 0; l < L_LAYERS; ++l) {
        node_gemm_kernel<false, false><<<N_NODES / 16, 256, 0, stream>>>(
            h, l1t + (size_t)l * D * D, nullptr, xf);
        edge_mlp_kernel<<<E_EDGES / 64, 256, 0, stream>>>(
            ea, el, perm, w1b + (size_t)l * D * 128, mlp_b1 + (size_t)l * D,
            w2b + (size_t)l * D * D, mlp_b2 + (size_t)l * D, wf);
        segsum_kernel<<<N_NODES / 4, 256, 0, stream>>>(wf, xf, row_start, src_p, m_i);
        node_gemm_kernel<true, true><<<N_NODES / 16, 256, 0, stream>>>(
            m_i, l2t + (size_t)l * D * D, lin2_b + (size_t)l * D, m);
        update_kernel<<<N_NODES / 16, 256, 0, stream>>>(
            h, m, lwt + (size_t)l * 2 * D * D, lin_b + (size_t)l * D);
    }

    hipMemcpyAsync(d_out, h, ND * sizeof(float), hipMemcpyDeviceToDevice, stream);
}

// Round 3
// 1618.744 us; speedup vs baseline: 2.8605x; 1.4030x over previous
//
#include <hip/hip_runtime.h>

#define N_NODES 20000
#define D 128
#define E_EDGES 320000
#define G 100
#define L_LAYERS 6
#define IN_DIM 5
#define ZROW (IN_DIM + D)
#define CUTOFF_V 10.0f
#define LOG2F_ 0.69314718055994530942f

typedef __attribute__((ext_vector_type(8))) short bf16x8;
typedef __attribute__((ext_vector_type(4))) float f32x4;
typedef unsigned short ushort_t;
typedef unsigned int uint_t;

__device__ __forceinline__ float sspf(float x) {
    // softplus(x)-log2 via fast hw exp/log (log arg in (1,2], well conditioned)
    return fmaxf(x, 0.0f) + __logf(1.0f + __expf(-fabsf(x))) - LOG2F_;
}

__device__ __forceinline__ ushort_t f2bf(float f) {
    union { float f; uint_t u; } x; x.f = f;
    uint_t r = ((x.u >> 16) & 1u) + 0x7fffu;
    return (ushort_t)((x.u + r) >> 16);
}

__device__ __forceinline__ uint_t pack2(float a, float b) {
    return (uint_t)f2bf(a) | ((uint_t)f2bf(b) << 16);
}

__device__ __forceinline__ f32x4 mfma_bf16(bf16x8 a, bf16x8 b, f32x4 c) {
    return __builtin_amdgcn_mfma_f32_16x16x32_bf16(a, b, c, 0, 0, 0);
}

// ---------------------------------------------------------------------------
__global__ void embed_kernel(const float* __restrict__ z,
                             const float* __restrict__ ew,
                             const float* __restrict__ eb,
                             float* __restrict__ h) {
    int n = blockIdx.x;
    int d = threadIdx.x;
    const float* zr = z + (size_t)n * ZROW;
    float acc = eb[d] + zr[IN_DIM + d];
#pragma unroll
    for (int k = 0; k < IN_DIM; ++k) acc += zr[k] * ew[d * IN_DIM + k];
    h[(size_t)n * D + d] = acc;
}

// ---------------------------------------------------------------------------
// mlp_w1 [L][D][G] -> bf16 [L][D][128] zero-padded in k
__global__ void convw1_kernel(const float* __restrict__ w1, ushort_t* __restrict__ out) {
    int idx = blockIdx.x * 256 + threadIdx.x;
    int k = idx & 127;
    int nl = idx >> 7;
    out[idx] = (k < G) ? f2bf(w1[(size_t)nl * G + k]) : (ushort_t)0;
}

__global__ void castbf_kernel(const float* __restrict__ src, ushort_t* __restrict__ dst) {
    int i = blockIdx.x * 256 + threadIdx.x;
    dst[i] = f2bf(src[i]);
}

// ---------------------------------------------------------------------------
// CSR build (edge graph constant across layers)
__global__ void hist_kernel(const int* __restrict__ ei, int* __restrict__ deg) {
    int e = blockIdx.x * 256 + threadIdx.x;
    atomicAdd(&deg[ei[E_EDGES + e]], 1);
}

__global__ __launch_bounds__(1024) void scan_kernel(const int* __restrict__ deg,
                                                    int* __restrict__ row_start,
                                                    int* __restrict__ cursor) {
    __shared__ int wsum[16];
    int t = threadIdx.x;
    const int CH = (N_NODES + 1023) / 1024;
    int base = t * CH;
    int s = 0;
    for (int i = 0; i < CH; ++i) {
        int idx = base + i;
        if (idx < N_NODES) s += deg[idx];
    }
    int lane = t & 63, wid = t >> 6;
    int v = s;
    for (int o = 1; o < 64; o <<= 1) {
        int u = __shfl_up(v, o, 64);
        if (lane >= o) v += u;
    }
    if (lane == 63) wsum[wid] = v;
    __syncthreads();
    if (t == 0) {
        int acc = 0;
        for (int i = 0; i < 16; ++i) { int tmp = wsum[i]; wsum[i] = acc; acc += tmp; }
    }
    __syncthreads();
    int run = v - s + wsum[wid];
    for (int i = 0; i < CH; ++i) {
        int idx = base + i;
        if (idx < N_NODES) {
            row_start[idx] = run;
            cursor[idx] = run;
            run += deg[idx];
        }
    }
    if (t == 0) row_start[N_NODES] = E_EDGES;
}

__global__ void scatter_perm_kernel(const int* __restrict__ ei, int* __restrict__ cursor,
                                    int* __restrict__ perm, int* __restrict__ src_p) {
    int e = blockIdx.x * 256 + threadIdx.x;
    int d = ei[E_EDGES + e];
    int p = atomicAdd(&cursor[d], 1);
    perm[p] = e;
    src_p[p] = ei[e];
}

// ---------------------------------------------------------------------------
// Fused edge MLP, transposed MFMA orientation:
//   GEMM1: D1[m=ucol][n=edge]  = W1 . attr^T   (A = W1 rows from global)
//   GEMM2: D2[m=wcol][n=edge]  = W2 . u^T
// 128 edges/block, 4 waves, each wave owns a private 32-row LDS strip
// (no __syncthreads anywhere). LDS stride 136 ushorts kills bank conflicts.
__global__ __launch_bounds__(256) void edge_mlp_kernel(
    const float* __restrict__ edge_attr, const float* __restrict__ el,
    const int* __restrict__ perm,
    const ushort_t* __restrict__ w1b, const float* __restrict__ b1,
    const ushort_t* __restrict__ w2b, const float* __restrict__ b2,
    ushort_t* __restrict__ wf) {
    __shared__ __align__(16) ushort_t sT[128][136];
    __shared__ int s_pe[128];
    __shared__ float s_cm[128];

    int t = threadIdx.x, lane = t & 63, wid = t >> 6;
    int c = lane & 15, quad = lane >> 4;
    int e0 = blockIdx.x * 128, rbase = wid * 32;

    if (lane < 32) {
        int pe = perm[e0 + rbase + lane];
        s_pe[rbase + lane] = pe;
        s_cm[rbase + lane] = (el[pe] <= CUTOFF_V) ? 1.0f : 0.0f;
    }
    // stage own 32 rows of attr (fp32 gather -> bf16 LDS, pad k to 128)
#pragma unroll
    for (int i = 0; i < 16; ++i) {
        int idx = i * 64 + lane;
        int r = idx >> 5, ch = idx & 31;
        float4 v = make_float4(0.f, 0.f, 0.f, 0.f);
        if (ch < 25) {
            int pe = s_pe[rbase + r];
            v = *(const float4*)(edge_attr + (size_t)pe * G + ch * 4);
        }
        uint2 p; p.x = pack2(v.x, v.y); p.y = pack2(v.z, v.w);
        *(uint2*)(&sT[rbase + r][ch * 4]) = p;
    }

    f32x4 acc[2][8];
#pragma unroll
    for (int st = 0; st < 2; ++st)
#pragma unroll
        for (int ct = 0; ct < 8; ++ct) acc[st][ct] = (f32x4){0.f, 0.f, 0.f, 0.f};

    // GEMM1
#pragma unroll
    for (int ks = 0; ks < 4; ++ks) {
        int koff = ks * 32 + quad * 8;
        bf16x8 b0 = *(const bf16x8*)(&sT[rbase + c][koff]);
        bf16x8 b1v = *(const bf16x8*)(&sT[rbase + 16 + c][koff]);
#pragma unroll
        for (int ct = 0; ct < 8; ++ct) {
            bf16x8 a = *(const bf16x8*)(w1b + (size_t)(ct * 16 + c) * 128 + koff);
            acc[0][ct] = mfma_bf16(a, b0, acc[0][ct]);
            acc[1][ct] = mfma_bf16(a, b1v, acc[1][ct]);
        }
    }
    // epilogue1: u = ssp(acc + b1) -> sT (lane holds 4 consecutive ucols of one edge)
#pragma unroll
    for (int st = 0; st < 2; ++st)
#pragma unroll
        for (int ct = 0; ct < 8; ++ct) {
            int col = ct * 16 + quad * 4;
            float4 bv = *(const float4*)(b1 + col);
            uint2 p;
            p.x = pack2(sspf(acc[st][ct][0] + bv.x), sspf(acc[st][ct][1] + bv.y));
            p.y = pack2(sspf(acc[st][ct][2] + bv.z), sspf(acc[st][ct][3] + bv.w));
            *(uint2*)(&sT[rbase + st * 16 + c][col]) = p;
        }

    // GEMM2
#pragma unroll
    for (int st = 0; st < 2; ++st)
#pragma unroll
        for (int ct = 0; ct < 8; ++ct) acc[st][ct] = (f32x4){0.f, 0.f, 0.f, 0.f};
#pragma unroll
    for (int ks = 0; ks < 4; ++ks) {
        int koff = ks * 32 + quad * 8;
        bf16x8 b0 = *(const bf16x8*)(&sT[rbase + c][koff]);
        bf16x8 b1v = *(const bf16x8*)(&sT[rbase + 16 + c][koff]);
#pragma unroll
        for (int ct = 0; ct < 8; ++ct) {
            bf16x8 a = *(const bf16x8*)(w2b + (size_t)(ct * 16 + c) * 128 + koff);
            acc[0][ct] = mfma_bf16(a, b0, acc[0][ct]);
            acc[1][ct] = mfma_bf16(a, b1v, acc[1][ct]);
        }
    }
    // epilogue2: Wf = (acc + b2) * C -> direct 8B global stores
#pragma unroll
    for (int st = 0; st < 2; ++st) {
        int e = e0 + rbase + st * 16 + c;
        float cv = s_cm[rbase + st * 16 + c];
#pragma unroll
        for (int ct = 0; ct < 8; ++ct) {
            int col = ct * 16 + quad * 4;
            float4 bv = *(const float4*)(b2 + col);
            uint2 p;
            p.x = pack2((acc[st][ct][0] + bv.x) * cv, (acc[st][ct][1] + bv.y) * cv);
            p.y = pack2((acc[st][ct][2] + bv.z) * cv, (acc[st][ct][3] + bv.w) * cv);
            *(uint2*)(wf + (size_t)e * 128 + col) = p;
        }
    }
}

// ---------------------------------------------------------------------------
// Generic node GEMM on MFMA, same transposed orientation; 128 nodes/block.
// out[node][col] = (opt RES: resid +) (opt SSP: ssp)( W . in^T + bias )
// TWOK: K=256, second 128-chunk staged from in1 (concat for update layer).
template <bool HASB, bool SSP, bool RES, bool BF16OUT, bool TWOK>
__global__ __launch_bounds__(256) void node_mfma_kernel(
    const float* __restrict__ in0, const float* __restrict__ in1,
    const ushort_t* __restrict__ Wb, const float* __restrict__ bias,
    const float* __restrict__ resid, void* __restrict__ outp) {
    __shared__ __align__(16) ushort_t sT[128][136];
    const int WS = TWOK ? 256 : 128;
    int t = threadIdx.x, lane = t & 63, wid = t >> 6;
    int c = lane & 15, quad = lane >> 4;
    int n0 = blockIdx.x * 128, rbase = wid * 32;

    f32x4 acc[2][8];
#pragma unroll
    for (int st = 0; st < 2; ++st)
#pragma unroll
        for (int ct = 0; ct < 8; ++ct) acc[st][ct] = (f32x4){0.f, 0.f, 0.f, 0.f};

    const float* src = in0;
#pragma unroll 1
    for (int ph = 0; ph < (TWOK ? 2 : 1); ++ph) {
        // stage own 32 rows fp32 -> bf16 LDS
#pragma unroll
        for (int i = 0; i < 16; ++i) {
            int idx = i * 64 + lane;
            int r = idx >> 5, ch = idx & 31;
            int gr = n0 + rbase + r;
            float4 v = make_float4(0.f, 0.f, 0.f, 0.f);
            if (gr < N_NODES) v = *(const float4*)(src + (size_t)gr * 128 + ch * 4);
            uint2 p; p.x = pack2(v.x, v.y); p.y = pack2(v.z, v.w);
            *(uint2*)(&sT[rbase + r][ch * 4]) = p;
        }
        int kb = ph * 128;
#pragma unroll
        for (int ks = 0; ks < 4; ++ks) {
            int koff = ks * 32 + quad * 8;
            bf16x8 b0 = *(const bf16x8*)(&sT[rbase + c][koff]);
            bf16x8 b1v = *(const bf16x8*)(&sT[rbase + 16 + c][koff]);
#pragma unroll
            for (int ct = 0; ct < 8; ++ct) {
                bf16x8 a = *(const bf16x8*)(Wb + (size_t)(ct * 16 + c) * WS + kb + koff);
                acc[0][ct] = mfma_bf16(a, b0, acc[0][ct]);
                acc[1][ct] = mfma_bf16(a, b1v, acc[1][ct]);
            }
        }
        src = in1;
    }

#pragma unroll
    for (int st = 0; st < 2; ++st) {
        int node = n0 + rbase + st * 16 + c;
        if (node < N_NODES) {
#pragma unroll
            for (int ct = 0; ct < 8; ++ct) {
                int col = ct * 16 + quad * 4;
                float4 bv = make_float4(0.f, 0.f, 0.f, 0.f);
                if (HASB) bv = *(const float4*)(bias + col);
                float v0 = acc[st][ct][0] + bv.x;
                float v1 = acc[st][ct][1] + bv.y;
                float v2 = acc[st][ct][2] + bv.z;
                float v3 = acc[st][ct][3] + bv.w;
                if (SSP) { v0 = sspf(v0); v1 = sspf(v1); v2 = sspf(v2); v3 = sspf(v3); }
                if (RES) {
                    float4 rv = *(const float4*)(resid + (size_t)node * 128 + col);
                    v0 += rv.x; v1 += rv.y; v2 += rv.z; v3 += rv.w;
                }
                if (BF16OUT) {
                    uint2 p; p.x = pack2(v0, v1); p.y = pack2(v2, v3);
                    *(uint2*)((ushort_t*)outp + (size_t)node * 128 + col) = p;
                } else {
                    *(float4*)((float*)outp + (size_t)node * 128 + col) =
                        make_float4(v0, v1, v2, v3);
                }
            }
        }
    }
}

// ---------------------------------------------------------------------------
// Segment sum: one wave per dst node, 2 cols/lane; wf and xf both bf16.
__global__ __launch_bounds__(256) void segsum_kernel(
    const ushort_t* __restrict__ wf, const ushort_t* __restrict__ xf_bf,
    const int* __restrict__ row_start, const int* __restrict__ src_p,
    float* __restrict__ m_i) {
    int t = threadIdx.x, lane = t & 63;
    int n = blockIdx.x * 4 + (t >> 6);
    int beg = row_start[n], end = row_start[n + 1];
    float a0 = 0.f, a1 = 0.f;
    for (int i = beg; i < end; ++i) {
        uint_t w = *(const uint_t*)(wf + (size_t)i * 128 + lane * 2);
        uint_t x = *(const uint_t*)(xf_bf + (size_t)src_p[i] * 128 + lane * 2);
        a0 += __uint_as_float(w << 16) * __uint_as_float(x << 16);
        a1 += __uint_as_float(w & 0xffff0000u) * __uint_as_float(x & 0xffff0000u);
    }
    *(float2*)(m_i + (size_t)n * 128 + lane * 2) = make_float2(a0, a1);
}

// ---------------------------------------------------------------------------
extern "C" void kernel_launch(void* const* d_in, const int* in_sizes, int n_in,
                              void* d_out, int out_size, void* d_ws, size_t ws_size,
                              hipStream_t stream) {
    const float* z        = (const float*)d_in[0];
    const int*   ei       = (const int*)d_in[1];
    const float* el       = (const float*)d_in[2];
    const float* ea       = (const float*)d_in[3];
    const float* emblin_w = (const float*)d_in[4];
    const float* emblin_b = (const float*)d_in[5];
    const float* mlp_w1   = (const float*)d_in[6];
    const float* mlp_b1   = (const float*)d_in[7];
    const float* mlp_w2   = (const float*)d_in[8];
    const float* mlp_b2   = (const float*)d_in[9];
    const float* lin1_w   = (const float*)d_in[10];
    const float* lin2_w   = (const float*)d_in[11];
    const float* lin2_b   = (const float*)d_in[12];
    const float* lin_w    = (const float*)d_in[13];
    const float* lin_b    = (const float*)d_in[14];
    (void)in_sizes; (void)n_in; (void)out_size; (void)ws_size;

    const size_t ND = (size_t)N_NODES * D;
    float* ws   = (float*)d_ws;
    float* h    = ws;                // N*D fp32
    float* m_i  = h + ND;            // N*D fp32
    float* fend = m_i + ND;

    ushort_t* w1b   = (ushort_t*)fend;                     // L*D*128
    ushort_t* w2b   = w1b   + (size_t)L_LAYERS * D * 128;  // L*D*D
    ushort_t* lin1b = w2b   + (size_t)L_LAYERS * D * D;    // L*D*D
    ushort_t* lin2b = lin1b + (size_t)L_LAYERS * D * D;    // L*D*D
    ushort_t* linwb = lin2b + (size_t)L_LAYERS * D * D;    // L*D*256
    ushort_t* wf    = linwb + (size_t)L_LAYERS * D * 256;  // E*128
    ushort_t* xf_bf = wf    + (size_t)E_EDGES * 128;       // N*128
    int* ibase      = (int*)(xf_bf + ND);
    int* deg        = ibase;                 // N
    int* row_start  = deg + N_NODES;         // N+1
    int* cursor     = row_start + N_NODES + 1;
    int* perm       = cursor + N_NODES;      // E
    int* src_p      = perm + E_EDGES;        // E

    // one-time weight prep (all bf16, row-major [out][k] = A-fragment layout)
    convw1_kernel<<<(L_LAYERS * D * 128) / 256, 256, 0, stream>>>(mlp_w1, w1b);
    castbf_kernel<<<(L_LAYERS * D * D) / 256, 256, 0, stream>>>(mlp_w2, w2b);
    castbf_kernel<<<(L_LAYERS * D * D) / 256, 256, 0, stream>>>(lin1_w, lin1b);
    castbf_kernel<<<(L_LAYERS * D * D) / 256, 256, 0, stream>>>(lin2_w, lin2b);
    castbf_kernel<<<(L_LAYERS * D * 256) / 256, 256, 0, stream>>>(lin_w, linwb);

    // CSR build
    hipMemsetAsync(deg, 0, (size_t)N_NODES * sizeof(int), stream);
    hist_kernel<<<E_EDGES / 256, 256, 0, stream>>>(ei, deg);
    scan_kernel<<<1, 1024, 0, stream>>>(deg, row_start, cursor);
    scatter_perm_kernel<<<E_EDGES / 256, 256, 0, stream>>>(ei, cursor, perm, src_p);

    embed_kernel<<<N_NODES, D, 0, stream>>>(z, emblin_w, emblin_b, h);

    const int NBLK = (N_NODES + 127) / 128;   // 157
    for (int l = 0; l < L_LAYERS; ++l) {
        // xf_bf = h @ lin1^T   (bf16 out, no bias)
        node_mfma_kernel<false, false, false, true, false><<<NBLK, 256, 0, stream>>>(
            h, nullptr, lin1b + (size_t)l * D * D, nullptr, nullptr, xf_bf);
        edge_mlp_kernel<<<E_EDGES / 128, 256, 0, stream>>>(
            ea, el, perm, w1b + (size_t)l * D * 128, mlp_b1 + (size_t)l * D,
            w2b + (size_t)l * D * D, mlp_b2 + (size_t)l * D, wf);
        segsum_kernel<<<N_NODES / 4, 256, 0, stream>>>(wf, xf_bf, row_start, src_p, m_i);
        // m_i = ssp(m_i @ lin2^T + b)   (in place, fp32)
        node_mfma_kernel<true, true, false, false, false><<<NBLK, 256, 0, stream>>>(
            m_i, nullptr, lin2b + (size_t)l * D * D, lin2_b + (size_t)l * D,
            nullptr, m_i);
        // h = h + concat(h, m_i) @ lin_w^T + b   (in place)
        node_mfma_kernel<true, false, true, false, true><<<NBLK, 256, 0, stream>>>(
            h, m_i, linwb + (size_t)l * D * 256, lin_b + (size_t)l * D, h, h);
    }

    hipMemcpyAsync(d_out, h, ND * sizeof(float), hipMemcpyDeviceToDevice, stream);
}